// Round 11
// baseline (251.982 us; speedup 1.0000x reference)
//
#include <hip/hip_runtime.h>

// SLAYER 3-layer CUBA SNN — fused MFMA GEMM + leaky-IF scan (4 launches).
// R11: R7 structure (proven: stage->barrier->MFMA->barrier, kc=64, 4 blk/CU)
// with 32x32x16 bf16 MFMA (µbench 2382 vs 2075 TF; R7's L1 sits exactly at
// the 16x16x32 ceiling). R6's 32x32 attempt had 4-way LDS conflicts: lanes
// {r32,+8,+16,+24} shared one slot+bank-group. Fixed swizzle adds
// ((row>>3)&3)<<1 to the XOR so every 8-contiguous-lane phase reads 8
// distinct 16B slots = all 32 banks. A/B/C-D fragment layouts verified on HW
// by R6 (absmax 0.0). Weights: W = hi + lo bf16 planes; spikes exact in bf16.
// Layout m = b*128 + t: block holds full Z[t][o] history -> in-LDS scan.

typedef unsigned short ushort_t;
typedef unsigned int uint_t;
typedef __bf16 bf16x8 __attribute__((ext_vector_type(8)));
typedef float f32x16 __attribute__((ext_vector_type(16)));

#define O_TOT 1024

__device__ __forceinline__ void glds16(const ushort_t* g, ushort_t* l) {
  __builtin_amdgcn_global_load_lds(
      (const __attribute__((address_space(1))) uint_t*)g,
      (__attribute__((address_space(3))) uint_t*)l, 16, 0, 0);
}

__device__ __forceinline__ ushort_t f32_to_bf16_rne(float f) {
  uint_t u = __float_as_uint(f);
  u += 0x7FFFu + ((u >> 16) & 1u);
  return (ushort_t)(u >> 16);
}

// swizzle: physical 16B-slot for (row, logical k-slot u0)
__device__ __forceinline__ int swz(int row, int u0) {
  return u0 ^ (row & 7) ^ (((row >> 3) & 3) << 1);
}

// ---- prep: W1/W2 hi-lo split (float4, 4 elems/thread) + spike transpose ----
// blocks 0..2047: W1; 2048..3071: W2; 3072..4095: transpose.
__global__ __launch_bounds__(256) void prep(const float* __restrict__ W1,
                                            const float* __restrict__ W2,
                                            const float* __restrict__ spike,
                                            ushort_t* __restrict__ h1,
                                            ushort_t* __restrict__ l1,
                                            ushort_t* __restrict__ h2,
                                            ushort_t* __restrict__ l2,
                                            ushort_t* __restrict__ A1) {
  const int tid = threadIdx.x;
  if (blockIdx.x < 3072) {
    const float* W;
    ushort_t *hp, *lp;
    size_t e0;
    if (blockIdx.x < 2048) {
      W = W1; hp = h1; lp = l1;
      e0 = (size_t)blockIdx.x * 1024 + tid * 4;
    } else {
      W = W2; hp = h2; lp = l2;
      e0 = (size_t)(blockIdx.x - 2048) * 1024 + tid * 4;
    }
    float4 w = *(const float4*)(W + e0);
    ushort4 hv, lv;
    hv.x = f32_to_bf16_rne(w.x);
    hv.y = f32_to_bf16_rne(w.y);
    hv.z = f32_to_bf16_rne(w.z);
    hv.w = f32_to_bf16_rne(w.w);
    lv.x = f32_to_bf16_rne(w.x - __uint_as_float(((uint_t)hv.x) << 16));
    lv.y = f32_to_bf16_rne(w.y - __uint_as_float(((uint_t)hv.y) << 16));
    lv.z = f32_to_bf16_rne(w.z - __uint_as_float(((uint_t)hv.z) << 16));
    lv.w = f32_to_bf16_rne(w.w - __uint_as_float(((uint_t)hv.w) << 16));
    *(ushort4*)(hp + e0) = hv;
    *(ushort4*)(lp + e0) = lv;
    return;
  }
  __shared__ ushort_t lds[128 * 130];  // [i][t] padded, 33,280 B
  const int bid = blockIdx.x - 3072;   // 0..1023
  const int b = bid >> 4;
  const int i0 = (bid & 15) * 128;
#pragma unroll
  for (int it = 0; it < 16; ++it) {
    int p = it * 256 + tid;
    int i = p >> 5, tg = (p & 31) * 4;
    float4 v = *(const float4*)(spike + ((size_t)b * 2048 + i0 + i) * 128 + tg);
    lds[i * 130 + tg + 0] = (v.x != 0.0f) ? 0x3F80u : 0u;
    lds[i * 130 + tg + 1] = (v.y != 0.0f) ? 0x3F80u : 0u;
    lds[i * 130 + tg + 2] = (v.z != 0.0f) ? 0x3F80u : 0u;
    lds[i * 130 + tg + 3] = (v.w != 0.0f) ? 0x3F80u : 0u;
  }
  __syncthreads();
#pragma unroll
  for (int it = 0; it < 16; ++it) {
    int p = it * 256 + tid;
    int t = p >> 5, j = p & 31;  // j: uint2 index (4 ushorts)
    uint_t u0 = (uint_t)lds[(4 * j + 0) * 130 + t] | ((uint_t)lds[(4 * j + 1) * 130 + t] << 16);
    uint_t u1 = (uint_t)lds[(4 * j + 2) * 130 + t] | ((uint_t)lds[(4 * j + 3) * 130 + t] << 16);
    uint2* dst = (uint2*)(A1 + (size_t)(b * 128 + t) * 2048 + i0);
    dst[j] = make_uint2(u0, u1);
  }
}

// ------- fused GEMM (128m x 64o tile, kc64, 32x32x16, hi/lo bf16) + scan ----
__global__ __launch_bounds__(256, 4)
void gemm_scan(const ushort_t* __restrict__ A, const ushort_t* __restrict__ Bhi,
               const ushort_t* __restrict__ Blo, ushort_t* __restrict__ S,
               int K) {
  __shared__ float smemf[128 * 65];   // 33,280 B
  ushort_t* As = (ushort_t*)smemf;    // 128 x 64 k (16 KB)
  ushort_t* Bh = As + 8192;           // 64 x 64 (8 KB)
  ushort_t* Bl = Bh + 4096;           // 8 KB
  float* Zt = smemf;                  // [128 t][65] epilogue overlay

  const int tid = threadIdx.x;
  const int wave = tid >> 6, lane = tid & 63;
  const int b = blockIdx.y;
  const int m0 = b * 128;
  const int o0 = blockIdx.x * 64;
  const int qm = wave >> 1, qn = wave & 1;
  const int r32 = lane & 31, h = lane >> 5;

  f32x16 acc[2];
#pragma unroll
  for (int i = 0; i < 2; ++i)
#pragma unroll
    for (int r = 0; r < 16; ++r) acc[i][r] = 0.0f;

  // A staging: 1024 slots, 4 rounds/wave
  size_t gA[4];
  ushort_t* lA[4];
#pragma unroll
  for (int r = 0; r < 4; ++r) {
    int s = wave * 256 + r * 64 + lane;
    int row = s >> 3;
    gA[r] = (size_t)(m0 + row) * K + swz(row, s & 7) * 8;
    lA[r] = As + (size_t)(wave * 256 + r * 64) * 8;
  }
  // B: 512 slots/plane, 2 rounds/wave
  size_t gB[2];
  ushort_t *lBh[2], *lBl[2];
#pragma unroll
  for (int r = 0; r < 2; ++r) {
    int s = wave * 128 + r * 64 + lane;
    int row = s >> 3;
    gB[r] = (size_t)(o0 + row) * K + swz(row, s & 7) * 8;
    lBh[r] = Bh + (size_t)(wave * 128 + r * 64) * 8;
    lBl[r] = Bl + (size_t)(wave * 128 + r * 64) * 8;
  }

  // frag LDS offsets: k-step s (16 k), lane k = s*16 + h*8 -> slot u0 = s*2+h
  int aoff[2][4], boff[4];
#pragma unroll
  for (int i = 0; i < 2; ++i) {
    int row = qm * 64 + i * 32 + r32;
#pragma unroll
    for (int s = 0; s < 4; ++s) aoff[i][s] = row * 64 + swz(row, s * 2 + h) * 8;
  }
  {
    int row = qn * 32 + r32;
#pragma unroll
    for (int s = 0; s < 4; ++s) boff[s] = row * 64 + swz(row, s * 2 + h) * 8;
  }

  for (int kc = 0; kc < K; kc += 64) {
#pragma unroll
    for (int r = 0; r < 4; ++r) glds16(A + gA[r] + kc, lA[r]);
#pragma unroll
    for (int r = 0; r < 2; ++r) {
      glds16(Bhi + gB[r] + kc, lBh[r]);
      glds16(Blo + gB[r] + kc, lBl[r]);
    }
    __syncthreads();

#pragma unroll
    for (int s = 0; s < 4; ++s) {
      bf16x8 af0 = *(const bf16x8*)(As + aoff[0][s]);
      bf16x8 af1 = *(const bf16x8*)(As + aoff[1][s]);
      bf16x8 bh = *(const bf16x8*)(Bh + boff[s]);
      bf16x8 bl = *(const bf16x8*)(Bl + boff[s]);
      acc[0] = __builtin_amdgcn_mfma_f32_32x32x16_bf16(af0, bh, acc[0], 0, 0, 0);
      acc[1] = __builtin_amdgcn_mfma_f32_32x32x16_bf16(af1, bh, acc[1], 0, 0, 0);
      acc[0] = __builtin_amdgcn_mfma_f32_32x32x16_bf16(af0, bl, acc[0], 0, 0, 0);
      acc[1] = __builtin_amdgcn_mfma_f32_32x32x16_bf16(af1, bl, acc[1], 0, 0, 0);
    }
    __syncthreads();
  }

  // acc -> LDS Z-tile: C/D layout col=r32, row=(reg&3)+8*(reg>>2)+4*h (R6-verified)
#pragma unroll
  for (int i = 0; i < 2; ++i)
#pragma unroll
    for (int reg = 0; reg < 16; ++reg) {
      int t = qm * 64 + i * 32 + (reg & 3) + 8 * (reg >> 2) + 4 * h;
      Zt[t * 65 + qn * 32 + r32] = acc[i][reg];
    }
  __syncthreads();

  // fused leaky-IF scan: thread tid<64 owns o-column (o0+tid)
  if (tid < 64) {
#pragma clang fp contract(off)
    float cur = 0.0f, vol = 0.0f;
    const int o = o0 + tid;
    for (int t = 0; t < 128; ++t) {
      float z = Zt[t * 65 + tid];
      cur = cur * 0.7f;
      cur = cur + z;
      vol = vol * 0.2f;
      vol = vol + cur;
      float v = vol - 1.0f;
      float s = (v >= 0.0f) ? 1.0f : 0.0f;
      vol = vol * (1.0f - s);
      S[(size_t)(m0 + t) * O_TOT + o] = (v >= 0.0f) ? 0x3F80u : 0u;
    }
  }
}

// ---------- layer 3 fused: per-b dense (O=2, fp32) + scan + output ----------
__global__ __launch_bounds__(256) void gemm3_scan(const ushort_t* __restrict__ X,
                                                  const float* __restrict__ W3,
                                                  float* __restrict__ out) {
  __shared__ float w3s[2048];
  __shared__ float z3[256];  // [t*2 + o]
  __shared__ float sp[256];  // [o*128 + t]
  const int tid = threadIdx.x;
  const int b = blockIdx.x;
  for (int i = tid; i < 2048; i += 256) w3s[i] = W3[i];
  __syncthreads();
  const int wave = tid >> 6, lane = tid & 63;
  for (int tt = 0; tt < 32; ++tt) {
    int t = wave * 32 + tt;
    const uint_t* row = (const uint_t*)(X + (size_t)(b * 128 + t) * 1024) + lane * 8;
    float s0 = 0.0f, s1 = 0.0f;
#pragma unroll
    for (int jw = 0; jw < 8; ++jw) {
      uint_t u = row[jw];
      float x0 = __uint_as_float(u << 16);
      float x1 = __uint_as_float(u & 0xFFFF0000u);
      int i0 = lane * 16 + jw * 2;
      s0 = fmaf(x0, w3s[i0], s0);
      s1 = fmaf(x0, w3s[1024 + i0], s1);
      s0 = fmaf(x1, w3s[i0 + 1], s0);
      s1 = fmaf(x1, w3s[1024 + i0 + 1], s1);
    }
#pragma unroll
    for (int off = 32; off > 0; off >>= 1) {
      s0 += __shfl_down(s0, off);
      s1 += __shfl_down(s1, off);
    }
    if (lane == 0) {
      z3[t * 2] = s0;
      z3[t * 2 + 1] = s1;
    }
  }
  __syncthreads();
  if (tid < 2) {
#pragma clang fp contract(off)
    float cur = 0.0f, vol = 0.0f;
    for (int t = 0; t < 128; ++t) {
      float z = z3[t * 2 + tid];
      cur = cur * 0.7f;
      cur = cur + z;
      vol = vol * 0.2f;
      vol = vol + cur;
      float v = vol - 1.0f;
      float s = (v >= 0.0f) ? 1.0f : 0.0f;
      vol = vol * (1.0f - s);
      sp[tid * 128 + t] = s;
    }
  }
  __syncthreads();
  out[b * 256 + tid] = sp[tid];
}

extern "C" void kernel_launch(void* const* d_in, const int* in_sizes, int n_in,
                              void* d_out, int out_size, void* d_ws, size_t ws_size,
                              hipStream_t stream) {
  const float* spike = (const float*)d_in[0];  // [64, 2048, 128]
  const float* W1 = (const float*)d_in[1];     // [1024, 2048]
  const float* W2 = (const float*)d_in[2];     // [1024, 1024]
  const float* W3 = (const float*)d_in[3];     // [2, 1024]
  float* out = (float*)d_out;                  // [64, 2, 128]

  char* ws = (char*)d_ws;
  ushort_t* A1 = (ushort_t*)ws;                                 // 32 MB
  ushort_t* S2 = (ushort_t*)(ws + (size_t)32 * 1024 * 1024);    // 16 MB
  ushort_t* S3 = (ushort_t*)(ws + (size_t)48 * 1024 * 1024);    // 16 MB
  ushort_t* W1hi = (ushort_t*)(ws + (size_t)64 * 1024 * 1024);  // 4 MB
  ushort_t* W1lo = (ushort_t*)(ws + (size_t)68 * 1024 * 1024);  // 4 MB
  ushort_t* W2hi = (ushort_t*)(ws + (size_t)72 * 1024 * 1024);  // 2 MB
  ushort_t* W2lo = (ushort_t*)(ws + (size_t)74 * 1024 * 1024);  // 2 MB

  // blocks 0..2047: W1 split; 2048..3071: W2 split; 3072..4095: transpose
  prep<<<4096, 256, 0, stream>>>(W1, W2, spike, W1hi, W1lo, W2hi, W2lo, A1);
  // L1: M=8192 (b*128+t), K=2048, O=1024
  gemm_scan<<<dim3(16, 64), 256, 0, stream>>>(A1, W1hi, W1lo, S2, 2048);
  // L2: K=1024
  gemm_scan<<<dim3(16, 64), 256, 0, stream>>>(S2, W2hi, W2lo, S3, 1024);
  // L3 + final scan + output
  gemm3_scan<<<64, 256, 0, stream>>>(S3, W3, out);
}

// Round 12
// 236.717 us; speedup vs baseline: 1.0645x; 1.0645x over previous
//
#include <hip/hip_runtime.h>

// SLAYER 3-layer CUBA SNN — i8 3-plane MFMA GEMM + fused leaky-IF scan.
// W = 2^-8*q1 + 2^-15*q2 + 2^-22*q3 (i8 planes, |q|<=64, exact fp32
// residuals) -> Z = 2^-8*D1 + 2^-15*D2 + 2^-22*D3 with exact i32 MFMA accum.
// Per-weight err <= 2^-23: tighter than the bf16 hi/lo split that passed
// absmax 0.0 (R3-R7). Spikes exact in i8 (0/1 bytes).
// GEMM: mfma_i32_16x16x64_i8 (3944 TOPS, 1.9x bf16 16x16) with R7's PROVEN
// conflict-free frag geometry (fr=lane&15, q=lane>>4, one b128 per frag).
// Block 128m x 32o, wave = 64m x 16o (acc 4x3x4 = 48 VGPR), kc=64 bytes,
// launch_bounds(256,4); grid 2048 = exactly 2 rounds of 4 blocks/CU.
// LDS slot swizzle: phys = row*4 + (u ^ ((row>>1)&3)) -> 8-lane phases
// cover all 32 banks. Layout m = b*128 + t -> in-LDS scan epilogue.

typedef unsigned short ushort_t;
typedef unsigned int uint_t;
typedef unsigned char uchar_t;
typedef int i32x4 __attribute__((ext_vector_type(4)));

#define S1F 0.00390625f             // 2^-8
#define S2F 3.0517578125e-5f        // 2^-15
#define S3F 2.384185791015625e-7f   // 2^-22

__device__ __forceinline__ void glds16(const uchar_t* g, uchar_t* l) {
  __builtin_amdgcn_global_load_lds(
      (const __attribute__((address_space(1))) uint_t*)g,
      (__attribute__((address_space(3))) uint_t*)l, 16, 0, 0);
}

// ---- prep: W1/W2 -> 3 i8 planes (blocks 0..3071) + spike transpose ---------
__global__ __launch_bounds__(256) void prep(const float* __restrict__ W1,
                                            const float* __restrict__ W2,
                                            const float* __restrict__ spike,
                                            char* __restrict__ w1q1,
                                            char* __restrict__ w1q2,
                                            char* __restrict__ w1q3,
                                            char* __restrict__ w2q1,
                                            char* __restrict__ w2q2,
                                            char* __restrict__ w2q3,
                                            uchar_t* __restrict__ A1) {
  const int tid = threadIdx.x;
  if (blockIdx.x < 3072) {
    const float* W;
    char *p1, *p2, *p3;
    size_t e0;
    if (blockIdx.x < 2048) {
      W = W1; p1 = w1q1; p2 = w1q2; p3 = w1q3;
      e0 = (size_t)blockIdx.x * 1024 + tid * 4;
    } else {
      W = W2; p1 = w2q1; p2 = w2q2; p3 = w2q3;
      e0 = (size_t)(blockIdx.x - 2048) * 1024 + tid * 4;
    }
    float4 w = *(const float4*)(W + e0);
    char4 c1, c2, c3;
    float q, r;
#define QUANT(comp, f1, f2, f3)                    \
    q = rintf((comp) * 256.0f);  f1 = (char)(int)q; \
    r = (comp) - q * S1F;                           \
    q = rintf(r * 32768.0f);     f2 = (char)(int)q; \
    r = r - q * S2F;                                \
    q = rintf(r * 4194304.0f);   f3 = (char)(int)q;
    QUANT(w.x, c1.x, c2.x, c3.x)
    QUANT(w.y, c1.y, c2.y, c3.y)
    QUANT(w.z, c1.z, c2.z, c3.z)
    QUANT(w.w, c1.w, c2.w, c3.w)
#undef QUANT
    *(char4*)(p1 + e0) = c1;
    *(char4*)(p2 + e0) = c2;
    *(char4*)(p3 + e0) = c3;
    return;
  }
  // spike [b][i][t] f32 -> A1 [b*128+t][i] i8 (0/1)
  __shared__ uchar_t lds8[128 * 132];  // [i][t] padded
  const int bid = blockIdx.x - 3072;   // 0..1023
  const int b = bid >> 4;
  const int i0 = (bid & 15) * 128;
#pragma unroll
  for (int it = 0; it < 16; ++it) {
    int p = it * 256 + tid;
    int i = p >> 5, tg = (p & 31) * 4;
    float4 v = *(const float4*)(spike + ((size_t)b * 2048 + i0 + i) * 128 + tg);
    uint_t pk = (v.x != 0.0f ? 1u : 0u) | (v.y != 0.0f ? 1u : 0u) << 8 |
                (v.z != 0.0f ? 1u : 0u) << 16 | (v.w != 0.0f ? 1u : 0u) << 24;
    *(uint_t*)(lds8 + i * 132 + tg) = pk;
  }
  __syncthreads();
#pragma unroll
  for (int it = 0; it < 16; ++it) {
    int p = it * 256 + tid;
    int t = p >> 5, jw = p & 31;  // output uint (4 i-bytes)
    uint_t u = (uint_t)lds8[(4 * jw + 0) * 132 + t] |
               ((uint_t)lds8[(4 * jw + 1) * 132 + t] << 8) |
               ((uint_t)lds8[(4 * jw + 2) * 132 + t] << 16) |
               ((uint_t)lds8[(4 * jw + 3) * 132 + t] << 24);
    *(uint_t*)(A1 + (size_t)(b * 128 + t) * 2048 + i0 + jw * 4) = u;
  }
}

// ---- fused GEMM (128m x 32o, kc=64B, i8 3-plane) + leaky-IF scan -----------
__global__ __launch_bounds__(256, 4)
void gemm_scan(const uchar_t* __restrict__ A, const char* __restrict__ Q1,
               const char* __restrict__ Q2, const char* __restrict__ Q3,
               uchar_t* __restrict__ S, int K) {
  __shared__ float smemf[128 * 33];  // 16,896 B; staging uses 14,336
  uchar_t* sA = (uchar_t*)smemf;     // A: 512 slots; B: 3 planes x 128 slots
  float* Zt = smemf;                 // [128 t][33] epilogue overlay

  const int tid = threadIdx.x;
  const int wave = tid >> 6, lane = tid & 63;
  const int m0 = blockIdx.y * 128;
  const int o0 = blockIdx.x * 32;
  const int qm = wave >> 1, qn = wave & 1;
  const int fr = lane & 15, q = lane >> 4;

  i32x4 acc[4][3];
#pragma unroll
  for (int i = 0; i < 4; ++i)
#pragma unroll
    for (int p = 0; p < 3; ++p) acc[i][p] = (i32x4){0, 0, 0, 0};

  // staging: 896 slots (A 512 + B 3x128), rounds it=0..3; it=3 waves 0,1 only
  const char* qplanes[3] = {Q1, Q2, Q3};
  const uchar_t* gsrc[4];
  uchar_t* ldst[4];
#pragma unroll
  for (int it = 0; it < 4; ++it) {
    int s = it * 256 + tid;
    gsrc[it] = nullptr;
    if (s < 896) {
      ldst[it] = sA + (size_t)(it * 256 + wave * 64) * 16;
      if (s < 512) {
        int row = s >> 2, pu = s & 3;
        int u = pu ^ ((row >> 1) & 3);
        gsrc[it] = A + (size_t)(m0 + row) * K + u * 16;
      } else {
        int t2 = s - 512;
        int p = t2 >> 7, r = t2 & 127;
        int row = r >> 2, pu = r & 3;
        int u = pu ^ ((row >> 1) & 3);
        gsrc[it] = (const uchar_t*)qplanes[p] + (size_t)(o0 + row) * K + u * 16;
      }
    }
  }

  // frag LDS byte offsets (phys slot = row*4 + (q ^ ((row>>1)&3)))
  int aoff[4], boff[3];
#pragma unroll
  for (int i = 0; i < 4; ++i) {
    int row = qm * 64 + i * 16 + fr;
    aoff[i] = (row * 4 + (q ^ ((row >> 1) & 3))) * 16;
  }
  {
    int row = qn * 16 + fr;
    int phys = (row * 4 + (q ^ ((row >> 1) & 3))) * 16;
#pragma unroll
    for (int p = 0; p < 3; ++p) boff[p] = 8192 + p * 2048 + phys;
  }

  for (int kc = 0; kc < K; kc += 64) {
#pragma unroll
    for (int it = 0; it < 4; ++it)
      if (gsrc[it]) glds16(gsrc[it] + kc, ldst[it]);
    __syncthreads();

    i32x4 af[4], bq[3];
#pragma unroll
    for (int i = 0; i < 4; ++i) af[i] = *(const i32x4*)(sA + aoff[i]);
#pragma unroll
    for (int p = 0; p < 3; ++p) bq[p] = *(const i32x4*)(sA + boff[p]);
#pragma unroll
    for (int p = 0; p < 3; ++p)
#pragma unroll
      for (int i = 0; i < 4; ++i)
        acc[i][p] = __builtin_amdgcn_mfma_i32_16x16x64_i8(af[i], bq[p], acc[i][p], 0, 0, 0);
    __syncthreads();
  }

  // combine planes -> fp32, write Z-tile (C/D: col=fr, row=q*4+rr)
#pragma unroll
  for (int i = 0; i < 4; ++i)
#pragma unroll
    for (int rr = 0; rr < 4; ++rr) {
      int t = qm * 64 + i * 16 + q * 4 + rr;
      float z = (float)acc[i][0][rr] * S1F + (float)acc[i][1][rr] * S2F +
                (float)acc[i][2][rr] * S3F;
      Zt[t * 33 + qn * 16 + fr] = z;
    }
  __syncthreads();

  // fused leaky-IF scan: thread tid<32 owns o-column (o0+tid)
  if (tid < 32) {
#pragma clang fp contract(off)
    float cur = 0.0f, vol = 0.0f;
    const int o = o0 + tid;
    for (int t = 0; t < 128; ++t) {
      float z = Zt[t * 33 + tid];
      cur = cur * 0.7f;
      cur = cur + z;
      vol = vol * 0.2f;
      vol = vol + cur;
      float v = vol - 1.0f;
      float s = (v >= 0.0f) ? 1.0f : 0.0f;
      vol = vol * (1.0f - s);
      S[(size_t)(m0 + t) * 1024 + o] = (v >= 0.0f) ? 1u : 0u;
    }
  }
}

// ---------- layer 3 fused: per-b dense (O=2, fp32) + scan + output ----------
__global__ __launch_bounds__(256) void gemm3_scan(const uchar_t* __restrict__ X,
                                                  const float* __restrict__ W3,
                                                  float* __restrict__ out) {
  __shared__ float w3s[2048];
  __shared__ float z3[256];  // [t*2 + o]
  __shared__ float sp[256];  // [o*128 + t]
  const int tid = threadIdx.x;
  const int b = blockIdx.x;
  for (int i = tid; i < 2048; i += 256) w3s[i] = W3[i];
  __syncthreads();
  const int wave = tid >> 6, lane = tid & 63;
  for (int tt = 0; tt < 32; ++tt) {
    int t = wave * 32 + tt;
    const uint4* rp = (const uint4*)(X + (size_t)(b * 128 + t) * 1024);
    uint4 v = rp[lane];
    float s0 = 0.0f, s1 = 0.0f;
    const uint_t uw[4] = {v.x, v.y, v.z, v.w};
#pragma unroll
    for (int wq = 0; wq < 4; ++wq)
#pragma unroll
      for (int c = 0; c < 4; ++c) {
        float x = (float)((uw[wq] >> (8 * c)) & 1u);
        int i0 = lane * 16 + wq * 4 + c;
        s0 = fmaf(x, w3s[i0], s0);
        s1 = fmaf(x, w3s[1024 + i0], s1);
      }
#pragma unroll
    for (int off = 32; off > 0; off >>= 1) {
      s0 += __shfl_down(s0, off);
      s1 += __shfl_down(s1, off);
    }
    if (lane == 0) {
      z3[t * 2] = s0;
      z3[t * 2 + 1] = s1;
    }
  }
  __syncthreads();
  if (tid < 2) {
#pragma clang fp contract(off)
    float cur = 0.0f, vol = 0.0f;
    for (int t = 0; t < 128; ++t) {
      float z = z3[t * 2 + tid];
      cur = cur * 0.7f;
      cur = cur + z;
      vol = vol * 0.2f;
      vol = vol + cur;
      float v = vol - 1.0f;
      float s = (v >= 0.0f) ? 1.0f : 0.0f;
      vol = vol * (1.0f - s);
      sp[tid * 128 + t] = s;
    }
  }
  __syncthreads();
  out[b * 256 + tid] = sp[tid];
}

extern "C" void kernel_launch(void* const* d_in, const int* in_sizes, int n_in,
                              void* d_out, int out_size, void* d_ws, size_t ws_size,
                              hipStream_t stream) {
  const float* spike = (const float*)d_in[0];  // [64, 2048, 128]
  const float* W1 = (const float*)d_in[1];     // [1024, 2048]
  const float* W2 = (const float*)d_in[2];     // [1024, 1024]
  const float* W3 = (const float*)d_in[3];     // [2, 1024]
  float* out = (float*)d_out;                  // [64, 2, 128]

  char* ws = (char*)d_ws;
  const size_t MB = 1024 * 1024;
  uchar_t* A1 = (uchar_t*)ws;                  // 16 MB [8192][2048] i8
  uchar_t* S2 = (uchar_t*)(ws + 16 * MB);      // 8 MB  [8192][1024] i8
  uchar_t* S3 = (uchar_t*)(ws + 24 * MB);      // 8 MB
  char* w1q1 = ws + 32 * MB;                   // 2 MB each
  char* w1q2 = ws + 34 * MB;
  char* w1q3 = ws + 36 * MB;
  char* w2q1 = ws + 38 * MB;                   // 1 MB each
  char* w2q2 = ws + 39 * MB;
  char* w2q3 = ws + 40 * MB;

  // blocks 0..2047: W1 quant; 2048..3071: W2 quant; 3072..4095: transpose
  prep<<<4096, 256, 0, stream>>>(W1, W2, spike, w1q1, w1q2, w1q3, w2q1, w2q2,
                                 w2q3, A1);
  // L1: M=8192 (b*128+t), K=2048 B, O=1024 (32 o-tiles)
  gemm_scan<<<dim3(32, 64), 256, 0, stream>>>(A1, w1q1, w1q2, w1q3, S2, 2048);
  // L2: K=1024 B
  gemm_scan<<<dim3(32, 64), 256, 0, stream>>>(S2, w2q1, w2q2, w2q3, S3, 1024);
  // L3 + final scan + output
  gemm3_scan<<<64, 256, 0, stream>>>(S3, W3, out);
}

// Round 13
// 220.108 us; speedup vs baseline: 1.1448x; 1.0755x over previous
//
#include <hip/hip_runtime.h>

// SLAYER 3-layer CUBA SNN — i8 3-plane MFMA GEMM + fused leaky-IF scan.
// R13 = R12 with K-chunk doubled to 128 bytes: barrier count halves, MFMA per
// wave-chunk doubles to 24 — amortizes the per-chunk vmem drain that held
// R12's L1 at 36% of the i8 ceiling (26 us floor at 3944 TOPS).
// W = 2^-8*q1 + 2^-15*q2 + 2^-22*q3 (i8 planes, exact fp32 residuals);
// Z = 2^-8*D1 + 2^-15*D2 + 2^-22*D3, i32 MFMA accum exact; per-weight err
// <= 2^-23 (absmax 0.0 in R12). Spikes exact in i8.
// Frag geometry (proven conflict-free): fr=lane&15, q=lane>>4, b128 frags,
// slot swizzle phys = row*8 + (u0 ^ (row&7)), u0 = half*4 + q.
// Layout m = b*128 + t: block holds full Z[t][o] history -> in-LDS scan.

typedef unsigned short ushort_t;
typedef unsigned int uint_t;
typedef unsigned char uchar_t;
typedef int i32x4 __attribute__((ext_vector_type(4)));

#define S1F 0.00390625f             // 2^-8
#define S2F 3.0517578125e-5f        // 2^-15
#define S3F 2.384185791015625e-7f   // 2^-22

__device__ __forceinline__ void glds16(const uchar_t* g, uchar_t* l) {
  __builtin_amdgcn_global_load_lds(
      (const __attribute__((address_space(1))) uint_t*)g,
      (__attribute__((address_space(3))) uint_t*)l, 16, 0, 0);
}

// ---- prep: W1/W2 -> 3 i8 planes (blocks 0..3071) + spike transpose ---------
__global__ __launch_bounds__(256) void prep(const float* __restrict__ W1,
                                            const float* __restrict__ W2,
                                            const float* __restrict__ spike,
                                            char* __restrict__ w1q1,
                                            char* __restrict__ w1q2,
                                            char* __restrict__ w1q3,
                                            char* __restrict__ w2q1,
                                            char* __restrict__ w2q2,
                                            char* __restrict__ w2q3,
                                            uchar_t* __restrict__ A1) {
  const int tid = threadIdx.x;
  if (blockIdx.x < 3072) {
    const float* W;
    char *p1, *p2, *p3;
    size_t e0;
    if (blockIdx.x < 2048) {
      W = W1; p1 = w1q1; p2 = w1q2; p3 = w1q3;
      e0 = (size_t)blockIdx.x * 1024 + tid * 4;
    } else {
      W = W2; p1 = w2q1; p2 = w2q2; p3 = w2q3;
      e0 = (size_t)(blockIdx.x - 2048) * 1024 + tid * 4;
    }
    float4 w = *(const float4*)(W + e0);
    char4 c1, c2, c3;
    float q, r;
#define QUANT(comp, f1, f2, f3)                    \
    q = rintf((comp) * 256.0f);  f1 = (char)(int)q; \
    r = (comp) - q * S1F;                           \
    q = rintf(r * 32768.0f);     f2 = (char)(int)q; \
    r = r - q * S2F;                                \
    q = rintf(r * 4194304.0f);   f3 = (char)(int)q;
    QUANT(w.x, c1.x, c2.x, c3.x)
    QUANT(w.y, c1.y, c2.y, c3.y)
    QUANT(w.z, c1.z, c2.z, c3.z)
    QUANT(w.w, c1.w, c2.w, c3.w)
#undef QUANT
    *(char4*)(p1 + e0) = c1;
    *(char4*)(p2 + e0) = c2;
    *(char4*)(p3 + e0) = c3;
    return;
  }
  // spike [b][i][t] f32 -> A1 [b*128+t][i] i8 (0/1)
  __shared__ uchar_t lds8[128 * 132];  // [i][t] padded
  const int bid = blockIdx.x - 3072;   // 0..1023
  const int b = bid >> 4;
  const int i0 = (bid & 15) * 128;
#pragma unroll
  for (int it = 0; it < 16; ++it) {
    int p = it * 256 + tid;
    int i = p >> 5, tg = (p & 31) * 4;
    float4 v = *(const float4*)(spike + ((size_t)b * 2048 + i0 + i) * 128 + tg);
    uint_t pk = (v.x != 0.0f ? 1u : 0u) | (v.y != 0.0f ? 1u : 0u) << 8 |
                (v.z != 0.0f ? 1u : 0u) << 16 | (v.w != 0.0f ? 1u : 0u) << 24;
    *(uint_t*)(lds8 + i * 132 + tg) = pk;
  }
  __syncthreads();
#pragma unroll
  for (int it = 0; it < 16; ++it) {
    int p = it * 256 + tid;
    int t = p >> 5, jw = p & 31;  // output uint (4 i-bytes)
    uint_t u = (uint_t)lds8[(4 * jw + 0) * 132 + t] |
               ((uint_t)lds8[(4 * jw + 1) * 132 + t] << 8) |
               ((uint_t)lds8[(4 * jw + 2) * 132 + t] << 16) |
               ((uint_t)lds8[(4 * jw + 3) * 132 + t] << 24);
    *(uint_t*)(A1 + (size_t)(b * 128 + t) * 2048 + i0 + jw * 4) = u;
  }
}

// ---- fused GEMM (128m x 32o, kc=128B, i8 3-plane) + leaky-IF scan ----------
__global__ __launch_bounds__(256, 4)
void gemm_scan(const uchar_t* __restrict__ A, const char* __restrict__ Q1,
               const char* __restrict__ Q2, const char* __restrict__ Q3,
               uchar_t* __restrict__ S, int K) {
  __shared__ float smemf[7168];      // 28,672 B staging; Zt overlay 16,896 B
  uchar_t* sA = (uchar_t*)smemf;     // A: slots 0..1023; B: 1024 + p*256 + ...
  float* Zt = smemf;                 // [128 t][33] epilogue overlay

  const int tid = threadIdx.x;
  const int wave = tid >> 6, lane = tid & 63;
  const int m0 = blockIdx.y * 128;
  const int o0 = blockIdx.x * 32;
  const int qm = wave >> 1, qn = wave & 1;
  const int fr = lane & 15, q = lane >> 4;

  i32x4 acc[4][3];
#pragma unroll
  for (int i = 0; i < 4; ++i)
#pragma unroll
    for (int p = 0; p < 3; ++p) acc[i][p] = (i32x4){0, 0, 0, 0};

  // staging: 1792 slots (A 1024 + B 3x256), exactly 7 rounds of 256 threads.
  // phys slot s holds logical (row, u0 = (s&7) ^ (row&7)).
  const char* qplanes[3] = {Q1, Q2, Q3};
  const uchar_t* gsrc[7];
  uchar_t* ldst[7];
#pragma unroll
  for (int it = 0; it < 7; ++it) {
    int s = it * 256 + tid;
    ldst[it] = sA + (size_t)(it * 256 + wave * 64) * 16;
    if (s < 1024) {
      int row = s >> 3;
      int u0 = (s & 7) ^ (row & 7);
      gsrc[it] = A + (size_t)(m0 + row) * K + u0 * 16;
    } else {
      int t2 = s - 1024;
      int p = t2 >> 8, r = (t2 >> 3) & 31;
      int u0 = (t2 & 7) ^ (r & 7);
      gsrc[it] = (const uchar_t*)qplanes[p] + (size_t)(o0 + r) * K + u0 * 16;
    }
  }

  // frag LDS byte offsets per k-half hh: u0 = hh*4 + q
  int aoff[4][2], boff[3][2];
#pragma unroll
  for (int i = 0; i < 4; ++i) {
    int row = qm * 64 + i * 16 + fr;
#pragma unroll
    for (int hh = 0; hh < 2; ++hh)
      aoff[i][hh] = (row * 8 + ((hh * 4 + q) ^ (row & 7))) * 16;
  }
  {
    int row = qn * 16 + fr;
#pragma unroll
    for (int hh = 0; hh < 2; ++hh) {
      int phys = row * 8 + ((hh * 4 + q) ^ (row & 7));
#pragma unroll
      for (int p = 0; p < 3; ++p)
        boff[p][hh] = (1024 + p * 256 + phys) * 16;
    }
  }

  for (int kc = 0; kc < K; kc += 128) {
#pragma unroll
    for (int it = 0; it < 7; ++it) glds16(gsrc[it] + kc, ldst[it]);
    __syncthreads();

#pragma unroll
    for (int hh = 0; hh < 2; ++hh) {
      i32x4 af[4], bq[3];
#pragma unroll
      for (int i = 0; i < 4; ++i) af[i] = *(const i32x4*)(sA + aoff[i][hh]);
#pragma unroll
      for (int p = 0; p < 3; ++p) bq[p] = *(const i32x4*)(sA + boff[p][hh]);
#pragma unroll
      for (int p = 0; p < 3; ++p)
#pragma unroll
        for (int i = 0; i < 4; ++i)
          acc[i][p] = __builtin_amdgcn_mfma_i32_16x16x64_i8(af[i], bq[p], acc[i][p], 0, 0, 0);
    }
    __syncthreads();
  }

  // combine planes -> fp32, write Z-tile (C/D: col=fr, row=q*4+rr)
#pragma unroll
  for (int i = 0; i < 4; ++i)
#pragma unroll
    for (int rr = 0; rr < 4; ++rr) {
      int t = qm * 64 + i * 16 + q * 4 + rr;
      float z = (float)acc[i][0][rr] * S1F + (float)acc[i][1][rr] * S2F +
                (float)acc[i][2][rr] * S3F;
      Zt[t * 33 + qn * 16 + fr] = z;
    }
  __syncthreads();

  // fused leaky-IF scan: thread tid<32 owns o-column (o0+tid)
  if (tid < 32) {
#pragma clang fp contract(off)
    float cur = 0.0f, vol = 0.0f;
    const int o = o0 + tid;
    for (int t = 0; t < 128; ++t) {
      float z = Zt[t * 33 + tid];
      cur = cur * 0.7f;
      cur = cur + z;
      vol = vol * 0.2f;
      vol = vol + cur;
      float v = vol - 1.0f;
      float s = (v >= 0.0f) ? 1.0f : 0.0f;
      vol = vol * (1.0f - s);
      S[(size_t)(m0 + t) * 1024 + o] = (v >= 0.0f) ? 1u : 0u;
    }
  }
}

// ---------- layer 3 fused: per-b dense (O=2, fp32) + scan + output ----------
__global__ __launch_bounds__(256) void gemm3_scan(const uchar_t* __restrict__ X,
                                                  const float* __restrict__ W3,
                                                  float* __restrict__ out) {
  __shared__ float w3s[2048];
  __shared__ float z3[256];  // [t*2 + o]
  __shared__ float sp[256];  // [o*128 + t]
  const int tid = threadIdx.x;
  const int b = blockIdx.x;
  for (int i = tid; i < 2048; i += 256) w3s[i] = W3[i];
  __syncthreads();
  const int wave = tid >> 6, lane = tid & 63;
  for (int tt = 0; tt < 32; ++tt) {
    int t = wave * 32 + tt;
    const uint4* rp = (const uint4*)(X + (size_t)(b * 128 + t) * 1024);
    uint4 v = rp[lane];
    float s0 = 0.0f, s1 = 0.0f;
    const uint_t uw[4] = {v.x, v.y, v.z, v.w};
#pragma unroll
    for (int wq = 0; wq < 4; ++wq)
#pragma unroll
      for (int c = 0; c < 4; ++c) {
        float x = (float)((uw[wq] >> (8 * c)) & 1u);
        int i0 = lane * 16 + wq * 4 + c;
        s0 = fmaf(x, w3s[i0], s0);
        s1 = fmaf(x, w3s[1024 + i0], s1);
      }
#pragma unroll
    for (int off = 32; off > 0; off >>= 1) {
      s0 += __shfl_down(s0, off);
      s1 += __shfl_down(s1, off);
    }
    if (lane == 0) {
      z3[t * 2] = s0;
      z3[t * 2 + 1] = s1;
    }
  }
  __syncthreads();
  if (tid < 2) {
#pragma clang fp contract(off)
    float cur = 0.0f, vol = 0.0f;
    for (int t = 0; t < 128; ++t) {
      float z = z3[t * 2 + tid];
      cur = cur * 0.7f;
      cur = cur + z;
      vol = vol * 0.2f;
      vol = vol + cur;
      float v = vol - 1.0f;
      float s = (v >= 0.0f) ? 1.0f : 0.0f;
      vol = vol * (1.0f - s);
      sp[tid * 128 + t] = s;
    }
  }
  __syncthreads();
  out[b * 256 + tid] = sp[tid];
}

extern "C" void kernel_launch(void* const* d_in, const int* in_sizes, int n_in,
                              void* d_out, int out_size, void* d_ws, size_t ws_size,
                              hipStream_t stream) {
  const float* spike = (const float*)d_in[0];  // [64, 2048, 128]
  const float* W1 = (const float*)d_in[1];     // [1024, 2048]
  const float* W2 = (const float*)d_in[2];     // [1024, 1024]
  const float* W3 = (const float*)d_in[3];     // [2, 1024]
  float* out = (float*)d_out;                  // [64, 2, 128]

  char* ws = (char*)d_ws;
  const size_t MB = 1024 * 1024;
  uchar_t* A1 = (uchar_t*)ws;                  // 16 MB [8192][2048] i8
  uchar_t* S2 = (uchar_t*)(ws + 16 * MB);      // 8 MB  [8192][1024] i8
  uchar_t* S3 = (uchar_t*)(ws + 24 * MB);      // 8 MB
  char* w1q1 = ws + 32 * MB;                   // 2 MB each
  char* w1q2 = ws + 34 * MB;
  char* w1q3 = ws + 36 * MB;
  char* w2q1 = ws + 38 * MB;                   // 1 MB each
  char* w2q2 = ws + 39 * MB;
  char* w2q3 = ws + 40 * MB;

  // blocks 0..2047: W1 quant; 2048..3071: W2 quant; 3072..4095: transpose
  prep<<<4096, 256, 0, stream>>>(W1, W2, spike, w1q1, w1q2, w1q3, w2q1, w2q2,
                                 w2q3, A1);
  // L1: M=8192 (b*128+t), K=2048 B, O=1024 (32 o-tiles)
  gemm_scan<<<dim3(32, 64), 256, 0, stream>>>(A1, w1q1, w1q2, w1q3, S2, 2048);
  // L2: K=1024 B
  gemm_scan<<<dim3(32, 64), 256, 0, stream>>>(S2, w2q1, w2q2, w2q3, S3, 1024);
  // L3 + final scan + output
  gemm3_scan<<<64, 256, 0, stream>>>(S3, W3, out);
}